// Round 6
// baseline (4609.279 us; speedup 1.0000x reference)
//
#include <hip/hip_runtime.h>
#include <hip/hip_bf16.h>
#include <math.h>

// Problem constants
#define EMBED  512
#define HEADS  2
#define HDIM   256
#define NTEXT  64
#define NWORD  32
#define NVID   128
#define NFRM   64

// ---- dtype helpers (flag: 1 = inputs are fp32, 0 = bf16) ----
// Reference declares float32 storage, so f=1 is the expected world; the sniff
// keeps us correct if the harness ever hands bf16 instead.
__device__ __forceinline__ float ldin(const void* p, size_t i, int f) {
    if (f) return ((const float*)p)[i];
    return __bfloat162float(((const __hip_bfloat16*)p)[i]);
}
__device__ __forceinline__ unsigned short f2bf(float x) {
    __hip_bfloat16 h = __float2bfloat16(x);
    return *(unsigned short*)&h;
}
__device__ __forceinline__ float bf2f(unsigned short u) {
    __hip_bfloat16 h = *(__hip_bfloat16*)&u;
    return __bfloat162float(h);
}

// Dtype sniff on a weight array (values ~N(0, ~1/512) so |w| << 1).
// fp32 world: low halfwords are mantissa garbage (~50% have bf16-exp >= 127)
// or exactly 0 if values were pre-rounded to bf16. True-bf16 world: halfwords
// are bf16 patterns of tiny gaussians - never 0, never exp >= 127.
__device__ __forceinline__ int sniff_fp32(const void* w, int tid, int* sflag) {
    if (tid < 64) {
        const unsigned short* p = (const unsigned short*)w;
        const unsigned short lo = p[2 * tid];
        const unsigned long long mz = __ballot(lo == 0);
        const unsigned long long mg = __ballot(((lo >> 7) & 0xFF) >= 127);
        if (tid == 0) {
            *sflag = (__popcll(mz) >= 48 || __popcll(mg) >= 8) ? 1 : 0;
        }
    }
    __syncthreads();
    return *sflag;
}

// q head/half-slice projection: C[r][c] = sum_e text[b0*32 + r][e]*Wq[h*256+c][e]
// + bq[h*256+c], r in [0,1024) (texts b0..b0+31), c in [0,256). Output FP32
// (q rounding is text-fixed and would not average out over the vid mean).
// Grid (16,4), 64x64 tiles.
__global__ __launch_bounds__(256)
void gemm_qh(const void* __restrict__ A, const void* __restrict__ W,
             const void* __restrict__ bias, float* __restrict__ C, int h, int b0) {
    __shared__ float As[16][68];
    __shared__ float Ws[16][68];
    __shared__ int sflag;
    const int tid = threadIdx.x;
    const int f = sniff_fp32(W, tid, &sflag);
    const int bi = blockIdx.x * 64, bj = blockIdx.y * 64;
    const int tx = tid & 15, ty = tid >> 4;
    const int lrow = tid >> 2, lk = (tid & 3) * 4;
    float acc[4][4] = {};
    for (int k0 = 0; k0 < 512; k0 += 16) {
        #pragma unroll
        for (int u = 0; u < 4; ++u) {
            As[lk + u][lrow] = ldin(A, (size_t)(b0 * 32 + bi + lrow) * 512 + k0 + lk + u, f);
            Ws[lk + u][lrow] = ldin(W, ((size_t)(h * 256 + bj + lrow)) * 512 + k0 + lk + u, f);
        }
        __syncthreads();
        #pragma unroll
        for (int kk = 0; kk < 16; ++kk) {
            float a[4], w[4];
            #pragma unroll
            for (int u = 0; u < 4; ++u) { a[u] = As[kk][ty * 4 + u]; w[u] = Ws[kk][tx * 4 + u]; }
            #pragma unroll
            for (int i = 0; i < 4; ++i)
                #pragma unroll
                for (int j = 0; j < 4; ++j)
                    acc[i][j] += a[i] * w[j];
        }
        __syncthreads();
    }
    #pragma unroll
    for (int i = 0; i < 4; ++i) {
        const int r = bi + ty * 4 + i;
        #pragma unroll
        for (int j = 0; j < 4; ++j) {
            const int c = bj + tx * 4 + j;
            C[(size_t)r * 256 + c] = acc[i][j] + ldin(bias, h * 256 + c, f);
        }
    }
}

// Output projection sweep: A = acc fp32 [512][512] (row lr = bl*16 + tl for
// local text bl, word-pair tl). C_out[g][c] = (1/128)*sum_k A[lr][k]*Wo[c][k]
// + bo[c], g = (b0+bl)*32 + h*16 + tl. OUTPUT IS FP32 (reference dtype).
__global__ __launch_bounds__(256)
void gemm_outp(const float* __restrict__ A, const void* __restrict__ W,
               const void* __restrict__ bias, float* __restrict__ C,
               int h, int b0) {
    __shared__ float As[16][68];
    __shared__ float Ws[16][68];
    __shared__ int sflag;
    const int tid = threadIdx.x;
    const int f = sniff_fp32(W, tid, &sflag);
    const int bi = blockIdx.x * 64, bj = blockIdx.y * 64;
    const int tx = tid & 15, ty = tid >> 4;
    const int lrow = tid >> 2, lk = (tid & 3) * 4;
    float acc[4][4] = {};
    for (int k0 = 0; k0 < 512; k0 += 16) {
        #pragma unroll
        for (int u = 0; u < 4; ++u) {
            As[lk + u][lrow] = A[(size_t)(bi + lrow) * 512 + k0 + lk + u];
            Ws[lk + u][lrow] = ldin(W, (size_t)(bj + lrow) * 512 + k0 + lk + u, f);
        }
        __syncthreads();
        #pragma unroll
        for (int kk = 0; kk < 16; ++kk) {
            float a[4], w[4];
            #pragma unroll
            for (int u = 0; u < 4; ++u) { a[u] = As[kk][ty * 4 + u]; w[u] = Ws[kk][tx * 4 + u]; }
            #pragma unroll
            for (int i = 0; i < 4; ++i)
                #pragma unroll
                for (int j = 0; j < 4; ++j)
                    acc[i][j] += a[i] * w[j];
        }
        __syncthreads();
    }
    #pragma unroll
    for (int i = 0; i < 4; ++i) {
        const int lr = bi + ty * 4 + i;
        const int g  = (b0 + (lr >> 4)) * 32 + h * 16 + (lr & 15);
        #pragma unroll
        for (int j = 0; j < 4; ++j) {
            const int c = bj + tx * 4 + j;
            C[(size_t)g * 512 + c] = acc[i][j] * (1.f / 128.f) + ldin(bias, c, f);
        }
    }
}

// Attention sweep: one block per vid a (128 blocks). Fixed head h, texts
// b0..b0+31. Phase 1: k,v projection for (a,h) into LDS (bf16 - the rounding
// varies per vid and averages out in the 128-vid mean). Phase 2: per local
// text bl: logits -> softmax(frames) -> weighted-V, atomicAdd into acc
// (fp32 [512][512]: row = bl*16 + (t>>1), col = (t&1)*256 + d).
__global__ __launch_bounds__(256)
void attn_sweep(const void* __restrict__ video,
                const void* __restrict__ Wk, const void* __restrict__ bk,
                const void* __restrict__ Wv, const void* __restrict__ bv,
                const float* __restrict__ qh,
                float* __restrict__ acc, int h) {
    __shared__ float As[16][68];
    __shared__ float Ws[16][68];
    __shared__ unsigned short Kb[64][260];
    __shared__ unsigned short Vb[64][260];
    __shared__ float Qs[32][260];
    __shared__ float Ls[64][33];
    __shared__ int sflag;
    const int a   = blockIdx.x;
    const int tid = threadIdx.x;
    const int f = sniff_fp32(Wk, tid, &sflag);

    const int tx = tid & 15, ty = tid >> 4;
    const int lrow = tid >> 2, lk = (tid & 3) * 4;

    // ---- phase 1: k = video[a] @ Wk_h^T + bk_h ; v likewise ----
    for (int kv = 0; kv < 2; ++kv) {
        const void* W = kv ? Wv : Wk;
        const void* B = kv ? bv : bk;
        for (int dblk = 0; dblk < 4; ++dblk) {
            const int d0 = dblk * 64;
            float pacc[4][4] = {};
            for (int e0 = 0; e0 < 512; e0 += 16) {
                #pragma unroll
                for (int u = 0; u < 4; ++u) {
                    As[lk + u][lrow] = ldin(video, ((size_t)(a * 64 + lrow)) * 512 + e0 + lk + u, f);
                    Ws[lk + u][lrow] = ldin(W, ((size_t)(h * 256 + d0 + lrow)) * 512 + e0 + lk + u, f);
                }
                __syncthreads();
                #pragma unroll
                for (int kk = 0; kk < 16; ++kk) {
                    float av[4], wv_[4];
                    #pragma unroll
                    for (int u = 0; u < 4; ++u) { av[u] = As[kk][ty * 4 + u]; wv_[u] = Ws[kk][tx * 4 + u]; }
                    #pragma unroll
                    for (int i = 0; i < 4; ++i)
                        #pragma unroll
                        for (int j = 0; j < 4; ++j)
                            pacc[i][j] += av[i] * wv_[j];
                }
                __syncthreads();
            }
            #pragma unroll
            for (int i = 0; i < 4; ++i)
                #pragma unroll
                for (int j = 0; j < 4; ++j) {
                    const int d = d0 + tx * 4 + j;
                    const float val = pacc[i][j] + ldin(B, h * 256 + d, f);
                    if (kv) Vb[ty * 4 + i][d] = f2bf(val);
                    else    Kb[ty * 4 + i][d] = f2bf(val);
                }
        }
    }

    // ---- phase 2: loop over the 32 texts of this half ----
    const int vg = tid >> 4, tg = tid & 15;   // logits: frames {vg*4..+3}, t {2tg,2tg+1}
    const int tq = tid >> 5, dq = tid & 31;   // attn:   t {tq*4..+3}, d via dq

    for (int bl = 0; bl < 32; ++bl) {
        __syncthreads();   // protect Qs/Ls rewrite vs previous iteration (and Kb/Vb on bl=0)
        for (int idx = tid; idx < NWORD * HDIM; idx += 256) {
            const int t = idx >> 8, d = idx & 255;
            Qs[t][d] = qh[((size_t)(bl * NWORD + t)) * 256 + d];
        }
        __syncthreads();
        // logits[v][t] = (k . q) / 16
        {
            float lg[4][2] = {};
            for (int d = 0; d < HDIM; d += 4) {
                float q0[4], q1[4];
                #pragma unroll
                for (int u = 0; u < 4; ++u) { q0[u] = Qs[2 * tg][d + u]; q1[u] = Qs[2 * tg + 1][d + u]; }
                #pragma unroll
                for (int i = 0; i < 4; ++i) {
                    #pragma unroll
                    for (int u = 0; u < 4; ++u) {
                        const float kvv = bf2f(Kb[vg * 4 + i][d + u]);
                        lg[i][0] += kvv * q0[u];
                        lg[i][1] += kvv * q1[u];
                    }
                }
            }
            #pragma unroll
            for (int i = 0; i < 4; ++i) {
                Ls[vg * 4 + i][2 * tg]     = lg[i][0] * 0.0625f;
                Ls[vg * 4 + i][2 * tg + 1] = lg[i][1] * 0.0625f;
            }
        }
        __syncthreads();
        if (tid < NWORD) {
            const int t = tid;
            float m = -1e30f;
            for (int v = 0; v < NFRM; ++v) m = fmaxf(m, Ls[v][t]);
            float s = 0.f;
            for (int v = 0; v < NFRM; ++v) { const float e = __expf(Ls[v][t] - m); Ls[v][t] = e; s += e; }
            const float inv = 1.f / s;
            for (int v = 0; v < NFRM; ++v) Ls[v][t] *= inv;
        }
        __syncthreads();
        // attn[t][d] = sum_v w[v][t] * V[v][d]
        float acc0[4][4] = {};
        float acc1[4][4] = {};
        for (int v = 0; v < NFRM; ++v) {
            float kv0[4], kv1[4];
            #pragma unroll
            for (int u = 0; u < 4; ++u) { kv0[u] = bf2f(Vb[v][4 * dq + u]); kv1[u] = bf2f(Vb[v][128 + 4 * dq + u]); }
            #pragma unroll
            for (int i = 0; i < 4; ++i) {
                const float w = Ls[v][tq * 4 + i];
                #pragma unroll
                for (int u = 0; u < 4; ++u) { acc0[i][u] += w * kv0[u]; acc1[i][u] += w * kv1[u]; }
            }
        }
        // local remap: row = bl*16 + (t>>1), col = (t&1)*256 + d
        #pragma unroll
        for (int i = 0; i < 4; ++i) {
            const int t  = tq * 4 + i;
            float* dst = acc + ((size_t)(bl * 16 + (t >> 1))) * 512 + (t & 1) * 256;
            #pragma unroll
            for (int u = 0; u < 4; ++u) {
                atomicAdd(&dst[4 * dq + u],       acc0[i][u]);
                atomicAdd(&dst[128 + 4 * dq + u], acc1[i][u]);
            }
        }
    }
}

extern "C" void kernel_launch(void* const* d_in, const int* in_sizes, int n_in,
                              void* d_out, int out_size, void* d_ws, size_t ws_size,
                              hipStream_t stream) {
    const void* text  = d_in[0];
    const void* video = d_in[1];
    const void* Wq = d_in[2];
    const void* bq = d_in[3];
    const void* Wk = d_in[4];
    const void* bk = d_in[5];
    const void* Wv = d_in[6];
    const void* bv = d_in[7];
    const void* Wo = d_in[8];
    const void* bo = d_in[9];
    float* out = (float*)d_out;   // reference output dtype is float32

    // Workspace: exactly 2 MB.
    //   acc fp32 [512][512]  = 1 MB  (per-(head, text-half) mean accumulator)
    //   qh  fp32 [1024][256] = 1 MB  (q head-slice for one text-half)
    float* acc = (float*)d_ws;
    float* qh  = (float*)((char*)d_ws + (1u << 20));

    for (int h = 0; h < 2; ++h) {
        for (int half = 0; half < 2; ++half) {
            const int b0 = half * 32;
            gemm_qh<<<dim3(16, 4), 256, 0, stream>>>(text, Wq, bq, qh, h, b0);
            hipMemsetAsync(acc, 0, (1u << 20), stream);
            attn_sweep<<<dim3(NVID), 256, 0, stream>>>(video, Wk, bk, Wv, bv, qh, acc, h);
            gemm_outp<<<dim3(8, 8), 256, 0, stream>>>(acc, Wo, bo, out, h, b0);
        }
    }
}

// Round 7
// 631.661 us; speedup vs baseline: 7.2971x; 7.2971x over previous
//
#include <hip/hip_runtime.h>
#include <hip/hip_bf16.h>
#include <math.h>

// Problem constants
#define EMBED  512
#define HEADS  2
#define HDIM   256
#define NTEXT  64
#define NWORD  32
#define NVID   128
#define NFRM   64

typedef __attribute__((ext_vector_type(8))) short      short8;    // 8 bf16 = A/B frag
typedef __attribute__((ext_vector_type(4))) float      float4v;   // C/D frag
typedef __attribute__((ext_vector_type(4))) unsigned short ushort4v;

__device__ __forceinline__ unsigned short f2bf(float x) {
    __hip_bfloat16 h = __float2bfloat16(x);
    return *(unsigned short*)&h;
}

// ---------------------------------------------------------------------------
// qproj: q[r][c] = sum_e text[r][e] * Wq[c][e] + bq[c], bf16 out.
// M=2048, N=512, K=512. Grid (32,8), 256 threads (4 waves).
// Wave w: m-tile w*16; 4 n-tiles of 16. MFMA 16x16x32 bf16.
// Layouts (m89-verified): A[m=lane&15][k=quad*8+j]; B from row-major W[n][k]
// identically; C/D col=lane&15, row=quad*4+reg.
// ---------------------------------------------------------------------------
__global__ __launch_bounds__(256)
void qproj(const float* __restrict__ A, const float* __restrict__ W,
           const float* __restrict__ bias, unsigned short* __restrict__ C) {
    __shared__ __align__(16) unsigned short Ab[64][40];
    __shared__ __align__(16) unsigned short Wb[64][40];
    const int tid = threadIdx.x;
    const int bi = blockIdx.x * 64, bj = blockIdx.y * 64;
    const int w = tid >> 6, lane = tid & 63;
    const int lm = lane & 15, qd = lane >> 4;

    float4v acc[4];
    #pragma unroll
    for (int nt = 0; nt < 4; ++nt) acc[nt] = (float4v){0.f, 0.f, 0.f, 0.f};

    for (int k0 = 0; k0 < 512; k0 += 32) {
        #pragma unroll
        for (int it = 0; it < 2; ++it) {
            const int s = tid + it * 256;          // 0..511 float4-slots
            const int r = s >> 3, c4 = (s & 7) * 4;
            float4v fa = *(const float4v*)&A[(size_t)(bi + r) * 512 + k0 + c4];
            float4v fw = *(const float4v*)&W[(size_t)(bj + r) * 512 + k0 + c4];
            *(ushort4v*)&Ab[r][c4] = (ushort4v){f2bf(fa.x), f2bf(fa.y), f2bf(fa.z), f2bf(fa.w)};
            *(ushort4v*)&Wb[r][c4] = (ushort4v){f2bf(fw.x), f2bf(fw.y), f2bf(fw.z), f2bf(fw.w)};
        }
        __syncthreads();
        const short8 af = *(const short8*)&Ab[w * 16 + lm][qd * 8];
        #pragma unroll
        for (int nt = 0; nt < 4; ++nt) {
            const short8 bf = *(const short8*)&Wb[nt * 16 + lm][qd * 8];
            acc[nt] = __builtin_amdgcn_mfma_f32_16x16x32_bf16(af, bf, acc[nt], 0, 0, 0);
        }
        __syncthreads();
    }
    #pragma unroll
    for (int nt = 0; nt < 4; ++nt) {
        const int c = bj + nt * 16 + lm;
        const float bb = bias[c];
        #pragma unroll
        for (int reg = 0; reg < 4; ++reg) {
            const int r = bi + w * 16 + qd * 4 + reg;
            C[(size_t)r * 512 + c] = f2bf(acc[nt][reg] + bb);
        }
    }
}

// ---------------------------------------------------------------------------
// attn: one block per (vid a, head h), grid (128, 2). Texts b0..b0+31.
// Phase 1 (MFMA): K = video[a]@Wk_h^T + bk  -> LDS Kb[64 v][256 d] bf16
//                 V = video[a]@Wv_h^T + bv  -> LDS Vt[256 d][64 v] bf16 (transposed)
// Phase 2 per text: L = Q K^T /16 (MFMA) -> softmax over v (8-lane groups)
//                   -> P bf16 (LDS) -> attn = P V (MFMA)
//                   -> atomicAdd into acc[1024][512] (already output-row order:
//                      row = bl*32 + h*16 + (t>>1), col = (t&1)*256 + d)
// ---------------------------------------------------------------------------
__global__ __launch_bounds__(256)
void attn(const float* __restrict__ video,
          const float* __restrict__ Wk, const float* __restrict__ bk,
          const float* __restrict__ Wv, const float* __restrict__ bv,
          const unsigned short* __restrict__ q,   // bf16 [2048][512]
          float* __restrict__ acc, int b0) {
    const int a = blockIdx.x, h = blockIdx.y;
    const int tid = threadIdx.x;
    const int w = tid >> 6, lane = tid & 63;
    const int lm = lane & 15, qd = lane >> 4;

    // Union: video tile (64x520 bf16 = 66560 B) then Vt (256x72 bf16 = 36864 B)
    __shared__ __align__(16) unsigned char Ubuf[64 * 520 * 2];
    unsigned short (*Vid)[520] = (unsigned short (*)[520])Ubuf;
    unsigned short (*Vt)[72]   = (unsigned short (*)[72])Ubuf;
    __shared__ __align__(16) unsigned short Kb[64][264];
    __shared__ __align__(16) unsigned short Wc[256][40];
    __shared__ __align__(16) unsigned short Qb[32][264];
    __shared__ __align__(16) unsigned short Pb[32][72];
    __shared__ float Ls[32][68];

    // ---- phase 1a: stage video[a] fp32 -> bf16 LDS ----
    #pragma unroll 4
    for (int it = 0; it < 32; ++it) {
        const int s = tid + it * 256;              // 0..8191 float4-slots
        const int r = s >> 7, c4 = (s & 127) * 4;
        float4v f = *(const float4v*)&video[((size_t)(a * 64 + r)) * 512 + c4];
        *(ushort4v*)&Vid[r][c4] = (ushort4v){f2bf(f.x), f2bf(f.y), f2bf(f.z), f2bf(f.w)};
    }
    __syncthreads();

    // ---- phase 1b: K pass ----
    {
        float4v kacc[16];
        #pragma unroll
        for (int nt = 0; nt < 16; ++nt) kacc[nt] = (float4v){0.f, 0.f, 0.f, 0.f};
        for (int k0 = 0; k0 < 512; k0 += 32) {
            #pragma unroll
            for (int it = 0; it < 8; ++it) {
                const int s = tid + it * 256;      // 0..2047 float4-slots
                const int r = s >> 3, c4 = (s & 7) * 4;
                float4v f = *(const float4v*)&Wk[((size_t)(h * 256 + r)) * 512 + k0 + c4];
                *(ushort4v*)&Wc[r][c4] = (ushort4v){f2bf(f.x), f2bf(f.y), f2bf(f.z), f2bf(f.w)};
            }
            __syncthreads();
            const short8 af = *(const short8*)&Vid[w * 16 + lm][k0 + qd * 8];
            #pragma unroll
            for (int nt = 0; nt < 16; ++nt) {
                const short8 bf = *(const short8*)&Wc[nt * 16 + lm][qd * 8];
                kacc[nt] = __builtin_amdgcn_mfma_f32_16x16x32_bf16(af, bf, kacc[nt], 0, 0, 0);
            }
            __syncthreads();
        }
        #pragma unroll
        for (int nt = 0; nt < 16; ++nt) {
            const int d = nt * 16 + lm;
            const float bb = bk[h * 256 + d];
            #pragma unroll
            for (int reg = 0; reg < 4; ++reg)
                Kb[w * 16 + qd * 4 + reg][d] = f2bf(kacc[nt][reg] + bb);
        }
    }
    // ---- phase 1c: V pass ----
    {
        float4v vacc[16];
        #pragma unroll
        for (int nt = 0; nt < 16; ++nt) vacc[nt] = (float4v){0.f, 0.f, 0.f, 0.f};
        for (int k0 = 0; k0 < 512; k0 += 32) {
            #pragma unroll
            for (int it = 0; it < 8; ++it) {
                const int s = tid + it * 256;
                const int r = s >> 3, c4 = (s & 7) * 4;
                float4v f = *(const float4v*)&Wv[((size_t)(h * 256 + r)) * 512 + k0 + c4];
                *(ushort4v*)&Wc[r][c4] = (ushort4v){f2bf(f.x), f2bf(f.y), f2bf(f.z), f2bf(f.w)};
            }
            __syncthreads();
            const short8 af = *(const short8*)&Vid[w * 16 + lm][k0 + qd * 8];
            #pragma unroll
            for (int nt = 0; nt < 16; ++nt) {
                const short8 bf = *(const short8*)&Wc[nt * 16 + lm][qd * 8];
                vacc[nt] = __builtin_amdgcn_mfma_f32_16x16x32_bf16(af, bf, vacc[nt], 0, 0, 0);
            }
            __syncthreads();
        }
        // All Vid reads are complete (barrier above) -> safe to overwrite with Vt.
        #pragma unroll
        for (int nt = 0; nt < 16; ++nt) {
            const int d = nt * 16 + lm;
            const float bb = bv[h * 256 + d];
            *(ushort4v*)&Vt[d][w * 16 + qd * 4] =
                (ushort4v){f2bf(vacc[nt][0] + bb), f2bf(vacc[nt][1] + bb),
                           f2bf(vacc[nt][2] + bb), f2bf(vacc[nt][3] + bb)};
        }
    }

    // ---- phase 2: texts ----
    const int m0  = (w & 1) * 16;      // t-tile
    const int nb  = (w >> 1) * 2;      // QK n-tile pair
    const int nb2 = (w >> 1) * 8;      // PV n-tile octet

    for (int bl = 0; bl < 32; ++bl) {
        const int b = b0 + bl;
        __syncthreads();   // Vt/Kb ready (bl=0); Qb/Ls/Pb reuse (bl>0)
        // stage Q[b,h]: 32x256 bf16
        #pragma unroll
        for (int it = 0; it < 4; ++it) {
            const int s = tid + it * 256;          // 0..1023 short8-slots
            const int r = s >> 5, c8 = (s & 31) * 8;
            *(short8*)&Qb[r][c8] =
                *(const short8*)&q[((size_t)(b * 32 + r)) * 512 + h * 256 + c8];
        }
        __syncthreads();
        // L = Q K^T / 16 : M=32(t), N=64(v), K=256
        {
            float4v lacc[2];
            lacc[0] = (float4v){0.f, 0.f, 0.f, 0.f};
            lacc[1] = (float4v){0.f, 0.f, 0.f, 0.f};
            for (int k0 = 0; k0 < 256; k0 += 32) {
                const short8 af = *(const short8*)&Qb[m0 + lm][k0 + qd * 8];
                #pragma unroll
                for (int j = 0; j < 2; ++j) {
                    const short8 bf = *(const short8*)&Kb[(nb + j) * 16 + lm][k0 + qd * 8];
                    lacc[j] = __builtin_amdgcn_mfma_f32_16x16x32_bf16(af, bf, lacc[j], 0, 0, 0);
                }
            }
            #pragma unroll
            for (int j = 0; j < 2; ++j)
                #pragma unroll
                for (int reg = 0; reg < 4; ++reg)
                    Ls[m0 + qd * 4 + reg][(nb + j) * 16 + lm] = lacc[j][reg] * 0.0625f;
        }
        __syncthreads();
        // softmax over v (64) per t: 8 threads per row, shuffle-reduce
        {
            const int t = tid >> 3, s = tid & 7;
            float4v x0 = *(const float4v*)&Ls[t][s * 8];
            float4v x1 = *(const float4v*)&Ls[t][s * 8 + 4];
            float m = fmaxf(fmaxf(fmaxf(x0.x, x0.y), fmaxf(x0.z, x0.w)),
                            fmaxf(fmaxf(x1.x, x1.y), fmaxf(x1.z, x1.w)));
            m = fmaxf(m, __shfl_xor(m, 1));
            m = fmaxf(m, __shfl_xor(m, 2));
            m = fmaxf(m, __shfl_xor(m, 4));
            float e[8];
            e[0] = __expf(x0.x - m); e[1] = __expf(x0.y - m);
            e[2] = __expf(x0.z - m); e[3] = __expf(x0.w - m);
            e[4] = __expf(x1.x - m); e[5] = __expf(x1.y - m);
            e[6] = __expf(x1.z - m); e[7] = __expf(x1.w - m);
            float sm = e[0] + e[1] + e[2] + e[3] + e[4] + e[5] + e[6] + e[7];
            sm += __shfl_xor(sm, 1);
            sm += __shfl_xor(sm, 2);
            sm += __shfl_xor(sm, 4);
            const float inv = 1.f / sm;
            ushort4v p0 = {f2bf(e[0] * inv), f2bf(e[1] * inv), f2bf(e[2] * inv), f2bf(e[3] * inv)};
            ushort4v p1 = {f2bf(e[4] * inv), f2bf(e[5] * inv), f2bf(e[6] * inv), f2bf(e[7] * inv)};
            *(ushort4v*)&Pb[t][s * 8]     = p0;
            *(ushort4v*)&Pb[t][s * 8 + 4] = p1;
        }
        __syncthreads();
        // attn = P V : M=32(t), N=256(d), K=64(v)
        {
            float4v pacc[8];
            #pragma unroll
            for (int j = 0; j < 8; ++j) pacc[j] = (float4v){0.f, 0.f, 0.f, 0.f};
            #pragma unroll
            for (int k0 = 0; k0 < 64; k0 += 32) {
                const short8 af = *(const short8*)&Pb[m0 + lm][k0 + qd * 8];
                #pragma unroll
                for (int j = 0; j < 8; ++j) {
                    const short8 bf = *(const short8*)&Vt[(nb2 + j) * 16 + lm][k0 + qd * 8];
                    pacc[j] = __builtin_amdgcn_mfma_f32_16x16x32_bf16(af, bf, pacc[j], 0, 0, 0);
                }
            }
            // atomic accumulate (remapped, output-row order)
            #pragma unroll
            for (int j = 0; j < 8; ++j) {
                const int d = (nb2 + j) * 16 + lm;
                #pragma unroll
                for (int reg = 0; reg < 4; ++reg) {
                    const int t   = m0 + qd * 4 + reg;
                    const int row = bl * 32 + h * 16 + (t >> 1);
                    const int e   = (t & 1) * 256 + d;
                    atomicAdd(&acc[(size_t)row * 512 + e], pacc[j][reg]);
                }
            }
        }
    }
}

// ---------------------------------------------------------------------------
// Output projection (fp32 VALU - acc must not be bf16-rounded: the 0.2% rel
// error on acc values ~6.4 would inject ~1e-2 into the output).
// A = acc fp32 [1024][512]; out[rowoff+lr][c] = (1/128)*sum_k A[lr][k]*Wo[c][k] + bo[c]
// ---------------------------------------------------------------------------
__global__ __launch_bounds__(256)
void gemm_outp(const float* __restrict__ A, const float* __restrict__ W,
               const float* __restrict__ bias, float* __restrict__ C, int rowoff) {
    __shared__ float As[16][68];
    __shared__ float Ws[16][68];
    const int tid = threadIdx.x;
    const int bi = blockIdx.x * 64, bj = blockIdx.y * 64;
    const int tx = tid & 15, ty = tid >> 4;
    const int lrow = tid >> 2, lk = (tid & 3) * 4;
    float acc[4][4] = {};
    for (int k0 = 0; k0 < 512; k0 += 16) {
        #pragma unroll
        for (int u = 0; u < 4; ++u) {
            As[lk + u][lrow] = A[(size_t)(bi + lrow) * 512 + k0 + lk + u];
            Ws[lk + u][lrow] = W[(size_t)(bj + lrow) * 512 + k0 + lk + u];
        }
        __syncthreads();
        #pragma unroll
        for (int kk = 0; kk < 16; ++kk) {
            float a[4], w[4];
            #pragma unroll
            for (int u = 0; u < 4; ++u) { a[u] = As[kk][ty * 4 + u]; w[u] = Ws[kk][tx * 4 + u]; }
            #pragma unroll
            for (int i = 0; i < 4; ++i)
                #pragma unroll
                for (int j = 0; j < 4; ++j)
                    acc[i][j] += a[i] * w[j];
        }
        __syncthreads();
    }
    #pragma unroll
    for (int i = 0; i < 4; ++i) {
        const int g = rowoff + bi + ty * 4 + i;
        #pragma unroll
        for (int j = 0; j < 4; ++j) {
            const int c = bj + tx * 4 + j;
            C[(size_t)g * 512 + c] = acc[i][j] * (1.f / 128.f) + bias[c];
        }
    }
}

extern "C" void kernel_launch(void* const* d_in, const int* in_sizes, int n_in,
                              void* d_out, int out_size, void* d_ws, size_t ws_size,
                              hipStream_t stream) {
    const float* text  = (const float*)d_in[0];
    const float* video = (const float*)d_in[1];
    const float* Wq = (const float*)d_in[2];
    const float* bq = (const float*)d_in[3];
    const float* Wk = (const float*)d_in[4];
    const float* bk = (const float*)d_in[5];
    const float* Wv = (const float*)d_in[6];
    const float* bv = (const float*)d_in[7];
    const float* Wo = (const float*)d_in[8];
    const float* bo = (const float*)d_in[9];

    // ws: acc fp32 [1024][512] = 2 MB (per text-half mean accumulator).
    // q bf16 [2048][512] = 2 MB lives in d_out bytes [0,2MB).
    // Half order 1 -> 0 guarantees the out-projection never overwrites live q:
    //   half 1: reads q bytes [1,2MB), writes out bytes [2,4MB)
    //   half 0: reads q bytes [0,1MB), writes out bytes [0,2MB) (q dead)
    float* acc = (float*)d_ws;
    unsigned short* qbf = (unsigned short*)d_out;
    float* out = (float*)d_out;

    qproj<<<dim3(32, 8), 256, 0, stream>>>(text, Wq, bq, qbf);

    for (int half = 1; half >= 0; --half) {
        hipMemsetAsync(acc, 0, 1u << 21, stream);
        attn<<<dim3(NVID, HEADS), 256, 0, stream>>>(video, Wk, bk, Wv, bv, qbf, acc, half * 32);
        gemm_outp<<<dim3(16, 8), 256, 0, stream>>>(acc, Wo, bo, out, half * 1024);
    }
}

// Round 8
// 296.912 us; speedup vs baseline: 15.5240x; 2.1274x over previous
//
#include <hip/hip_runtime.h>
#include <hip/hip_bf16.h>
#include <math.h>

// Problem constants
#define EMBED  512
#define HEADS  2
#define HDIM   256
#define NTEXT  64
#define NWORD  32
#define NVID   128
#define NFRM   64

typedef __attribute__((ext_vector_type(8))) short      short8;    // 8 bf16 = A/B frag
typedef __attribute__((ext_vector_type(8))) unsigned short ushort8;
typedef __attribute__((ext_vector_type(4))) float      float4v;   // C/D frag
typedef __attribute__((ext_vector_type(4))) unsigned short ushort4v;

__device__ __forceinline__ unsigned short f2bf(float x) {
    __hip_bfloat16 h = __float2bfloat16(x);
    return *(unsigned short*)&h;
}

// ---------------------------------------------------------------------------
// qproj: q[r][c] = sum_e text[r][e] * Wq[c][e] + bq[c], bf16 out into d_out.
// M=2048, N=512, K=512. Grid (32,8), 256 threads.
// ---------------------------------------------------------------------------
__global__ __launch_bounds__(256)
void qproj(const float* __restrict__ A, const float* __restrict__ W,
           const float* __restrict__ bias, unsigned short* __restrict__ C) {
    __shared__ __align__(16) unsigned short Ab[64][40];
    __shared__ __align__(16) unsigned short Wb[64][40];
    const int tid = threadIdx.x;
    const int bi = blockIdx.x * 64, bj = blockIdx.y * 64;
    const int w = tid >> 6, lane = tid & 63;
    const int lm = lane & 15, qd = lane >> 4;

    float4v acc[4];
    #pragma unroll
    for (int nt = 0; nt < 4; ++nt) acc[nt] = (float4v){0.f, 0.f, 0.f, 0.f};

    for (int k0 = 0; k0 < 512; k0 += 32) {
        #pragma unroll
        for (int it = 0; it < 2; ++it) {
            const int s = tid + it * 256;
            const int r = s >> 3, c4 = (s & 7) * 4;
            float4v fa = *(const float4v*)&A[(size_t)(bi + r) * 512 + k0 + c4];
            float4v fw = *(const float4v*)&W[(size_t)(bj + r) * 512 + k0 + c4];
            *(ushort4v*)&Ab[r][c4] = (ushort4v){f2bf(fa.x), f2bf(fa.y), f2bf(fa.z), f2bf(fa.w)};
            *(ushort4v*)&Wb[r][c4] = (ushort4v){f2bf(fw.x), f2bf(fw.y), f2bf(fw.z), f2bf(fw.w)};
        }
        __syncthreads();
        const short8 af = *(const short8*)&Ab[w * 16 + lm][qd * 8];
        #pragma unroll
        for (int nt = 0; nt < 4; ++nt) {
            const short8 bf = *(const short8*)&Wb[nt * 16 + lm][qd * 8];
            acc[nt] = __builtin_amdgcn_mfma_f32_16x16x32_bf16(af, bf, acc[nt], 0, 0, 0);
        }
        __syncthreads();
    }
    #pragma unroll
    for (int nt = 0; nt < 4; ++nt) {
        const int c = bj + nt * 16 + lm;
        const float bb = bias[c];
        #pragma unroll
        for (int reg = 0; reg < 4; ++reg) {
            const int r = bi + w * 16 + qd * 4 + reg;
            C[(size_t)r * 512 + c] = f2bf(acc[nt][reg] + bb);
        }
    }
}

// ---------------------------------------------------------------------------
// kvproj: per (vid a, head h) block: K = video[a]@Wk_h^T+bk -> Kg[h][a][64][256]
// bf16; V likewise -> Vtg[h][a][256][64] (transposed). r7 phase-1 MFMA + spill.
// ---------------------------------------------------------------------------
__global__ __launch_bounds__(256)
void kvproj(const float* __restrict__ video,
            const float* __restrict__ Wk, const float* __restrict__ bk,
            const float* __restrict__ Wv, const float* __restrict__ bv,
            unsigned short* __restrict__ Kg, unsigned short* __restrict__ Vtg) {
    const int a = blockIdx.x, h = blockIdx.y;
    const int tid = threadIdx.x;
    const int w = tid >> 6, lane = tid & 63;
    const int lm = lane & 15, qd = lane >> 4;

    __shared__ __align__(16) unsigned char Ubuf[64 * 520 * 2];  // Vid then Vt
    unsigned short (*Vid)[520] = (unsigned short (*)[520])Ubuf;
    unsigned short (*Vt)[72]   = (unsigned short (*)[72])Ubuf;
    __shared__ __align__(16) unsigned short Kb[64][264];
    __shared__ __align__(16) unsigned short Wc[256][40];

    // stage video[a] fp32 -> bf16 LDS
    #pragma unroll 4
    for (int it = 0; it < 32; ++it) {
        const int s = tid + it * 256;
        const int r = s >> 7, c4 = (s & 127) * 4;
        float4v f = *(const float4v*)&video[((size_t)(a * 64 + r)) * 512 + c4];
        *(ushort4v*)&Vid[r][c4] = (ushort4v){f2bf(f.x), f2bf(f.y), f2bf(f.z), f2bf(f.w)};
    }
    __syncthreads();

    // K pass
    {
        float4v kacc[16];
        #pragma unroll
        for (int nt = 0; nt < 16; ++nt) kacc[nt] = (float4v){0.f, 0.f, 0.f, 0.f};
        for (int k0 = 0; k0 < 512; k0 += 32) {
            #pragma unroll
            for (int it = 0; it < 8; ++it) {
                const int s = tid + it * 256;
                const int r = s >> 3, c4 = (s & 7) * 4;
                float4v f = *(const float4v*)&Wk[((size_t)(h * 256 + r)) * 512 + k0 + c4];
                *(ushort4v*)&Wc[r][c4] = (ushort4v){f2bf(f.x), f2bf(f.y), f2bf(f.z), f2bf(f.w)};
            }
            __syncthreads();
            const short8 af = *(const short8*)&Vid[w * 16 + lm][k0 + qd * 8];
            #pragma unroll
            for (int nt = 0; nt < 16; ++nt) {
                const short8 bf = *(const short8*)&Wc[nt * 16 + lm][qd * 8];
                kacc[nt] = __builtin_amdgcn_mfma_f32_16x16x32_bf16(af, bf, kacc[nt], 0, 0, 0);
            }
            __syncthreads();
        }
        #pragma unroll
        for (int nt = 0; nt < 16; ++nt) {
            const int d = nt * 16 + lm;
            const float bb = bk[h * 256 + d];
            #pragma unroll
            for (int reg = 0; reg < 4; ++reg)
                Kb[w * 16 + qd * 4 + reg][d] = f2bf(kacc[nt][reg] + bb);
        }
    }
    // V pass
    {
        float4v vacc[16];
        #pragma unroll
        for (int nt = 0; nt < 16; ++nt) vacc[nt] = (float4v){0.f, 0.f, 0.f, 0.f};
        for (int k0 = 0; k0 < 512; k0 += 32) {
            #pragma unroll
            for (int it = 0; it < 8; ++it) {
                const int s = tid + it * 256;
                const int r = s >> 3, c4 = (s & 7) * 4;
                float4v f = *(const float4v*)&Wv[((size_t)(h * 256 + r)) * 512 + k0 + c4];
                *(ushort4v*)&Wc[r][c4] = (ushort4v){f2bf(f.x), f2bf(f.y), f2bf(f.z), f2bf(f.w)};
            }
            __syncthreads();
            const short8 af = *(const short8*)&Vid[w * 16 + lm][k0 + qd * 8];
            #pragma unroll
            for (int nt = 0; nt < 16; ++nt) {
                const short8 bf = *(const short8*)&Wc[nt * 16 + lm][qd * 8];
                vacc[nt] = __builtin_amdgcn_mfma_f32_16x16x32_bf16(af, bf, vacc[nt], 0, 0, 0);
            }
            __syncthreads();
        }
        // Vid fully consumed -> overwrite union with Vt (transposed V)
        #pragma unroll
        for (int nt = 0; nt < 16; ++nt) {
            const int d = nt * 16 + lm;
            const float bb = bv[h * 256 + d];
            *(ushort4v*)&Vt[d][w * 16 + qd * 4] =
                (ushort4v){f2bf(vacc[nt][0] + bb), f2bf(vacc[nt][1] + bb),
                           f2bf(vacc[nt][2] + bb), f2bf(vacc[nt][3] + bb)};
        }
    }
    __syncthreads();
    // spill Kb, Vt to global (coalesced 16B)
    const size_t kbase = (((size_t)h * 128 + a) * 64) * 256;
    #pragma unroll
    for (int i = 0; i < 8; ++i) {
        const int s = tid + i * 256;              // 0..2047
        const int v = s >> 5, c8 = (s & 31) * 8;
        *(ushort8*)&Kg[kbase + (size_t)v * 256 + c8] = *(const ushort8*)&Kb[v][c8];
    }
    const size_t vbase = (((size_t)h * 128 + a) * 256) * 64;
    #pragma unroll
    for (int i = 0; i < 8; ++i) {
        const int s = tid + i * 256;
        const int d = s >> 3, v8 = (s & 7) * 8;
        *(ushort8*)&Vtg[vbase + (size_t)d * 64 + v8] = *(const ushort8*)&Vt[d][v8];
    }
}

// ---------------------------------------------------------------------------
// attn_acc: grid (16 a-chunks, 2 h, 8 t-chunks), 512 threads (8 waves).
// Wave w owns text b = z*8+w. Loops over 8 vids of its chunk: coop-load
// K/Vt to LDS, per wave: QK (Q frags from global), shuffle softmax, P via
// wave-private LDS patch, PV accumulated in VGPRs across vids. One atomic
// pass at the end: 16.8M atomics total, no per-text barrier drains.
// ---------------------------------------------------------------------------
__global__ __launch_bounds__(512, 2)
void attn_acc(const unsigned short* __restrict__ Kg,
              const unsigned short* __restrict__ Vtg,
              const unsigned short* __restrict__ q,   // bf16 [2048][512]
              float* __restrict__ acc) {
    const int chunk = blockIdx.x;   // 8 vids each
    const int h = blockIdx.y;
    const int zb = blockIdx.z;
    const int tid = threadIdx.x;
    const int w = tid >> 6, lane = tid & 63;
    const int lm = lane & 15, qd = lane >> 4;
    const int b = zb * 8 + w;       // this wave's text

    __shared__ __align__(16) unsigned short Kb[64][264];
    __shared__ __align__(16) unsigned short Vt[256][72];
    __shared__ __align__(16) unsigned short Pb[8][32][72];

    float4v pacc[2][16];
    #pragma unroll
    for (int mt = 0; mt < 2; ++mt)
        #pragma unroll
        for (int nt = 0; nt < 16; ++nt) pacc[mt][nt] = (float4v){0.f, 0.f, 0.f, 0.f};

    for (int ai = 0; ai < 8; ++ai) {
        const int a = chunk * 8 + ai;
        __syncthreads();   // protect Kb/Vt overwrite vs previous iteration
        const size_t kbase = (((size_t)h * 128 + a) * 64) * 256;
        #pragma unroll
        for (int i = 0; i < 4; ++i) {
            const int s = tid + i * 512;           // 0..2047
            const int v = s >> 5, c8 = (s & 31) * 8;
            *(ushort8*)&Kb[v][c8] = *(const ushort8*)&Kg[kbase + (size_t)v * 256 + c8];
        }
        const size_t vbase = (((size_t)h * 128 + a) * 256) * 64;
        #pragma unroll
        for (int i = 0; i < 4; ++i) {
            const int s = tid + i * 512;
            const int d = s >> 3, v8 = (s & 7) * 8;
            *(ushort8*)&Vt[d][v8] = *(const ushort8*)&Vtg[vbase + (size_t)d * 64 + v8];
        }
        __syncthreads();

        // QK: L[t][v] = sum_d Q[t][d] K[v][d], t = mt*16+qd*4+reg, v = nt*16+lm
        float4v lacc[2][4];
        #pragma unroll
        for (int mt = 0; mt < 2; ++mt)
            #pragma unroll
            for (int nt = 0; nt < 4; ++nt) lacc[mt][nt] = (float4v){0.f, 0.f, 0.f, 0.f};
        for (int k0 = 0; k0 < 256; k0 += 32) {
            short8 bfr[4];
            #pragma unroll
            for (int nt = 0; nt < 4; ++nt)
                bfr[nt] = *(const short8*)&Kb[nt * 16 + lm][k0 + qd * 8];
            #pragma unroll
            for (int mt = 0; mt < 2; ++mt) {
                const short8 af = *(const short8*)
                    &q[((size_t)(b * 32 + mt * 16 + lm)) * 512 + h * 256 + k0 + qd * 8];
                #pragma unroll
                for (int nt = 0; nt < 4; ++nt)
                    lacc[mt][nt] = __builtin_amdgcn_mfma_f32_16x16x32_bf16(af, bfr[nt], lacc[mt][nt], 0, 0, 0);
            }
        }
        // softmax over v per t-row (in-lane over nt, cross-lane over lm group)
        #pragma unroll
        for (int mt = 0; mt < 2; ++mt) {
            #pragma unroll
            for (int reg = 0; reg < 4; ++reg) {
                float l0 = lacc[mt][0][reg] * 0.0625f;
                float l1 = lacc[mt][1][reg] * 0.0625f;
                float l2 = lacc[mt][2][reg] * 0.0625f;
                float l3 = lacc[mt][3][reg] * 0.0625f;
                float m = fmaxf(fmaxf(l0, l1), fmaxf(l2, l3));
                m = fmaxf(m, __shfl_xor(m, 1));
                m = fmaxf(m, __shfl_xor(m, 2));
                m = fmaxf(m, __shfl_xor(m, 4));
                m = fmaxf(m, __shfl_xor(m, 8));
                const float e0 = __expf(l0 - m), e1 = __expf(l1 - m);
                const float e2 = __expf(l2 - m), e3 = __expf(l3 - m);
                float s = e0 + e1 + e2 + e3;
                s += __shfl_xor(s, 1);
                s += __shfl_xor(s, 2);
                s += __shfl_xor(s, 4);
                s += __shfl_xor(s, 8);
                const float inv = 1.f / s;
                const int t = mt * 16 + qd * 4 + reg;
                Pb[w][t][0 * 16 + lm] = f2bf(e0 * inv);
                Pb[w][t][1 * 16 + lm] = f2bf(e1 * inv);
                Pb[w][t][2 * 16 + lm] = f2bf(e2 * inv);
                Pb[w][t][3 * 16 + lm] = f2bf(e3 * inv);
            }
        }
        // PV: attn[t][d] += sum_v P[t][v] Vt[d][v]  (wave-private Pb, no barrier)
        #pragma unroll
        for (int k0 = 0; k0 < 64; k0 += 32) {
            short8 paf[2];
            #pragma unroll
            for (int mt = 0; mt < 2; ++mt)
                paf[mt] = *(const short8*)&Pb[w][mt * 16 + lm][k0 + qd * 8];
            #pragma unroll
            for (int nt = 0; nt < 16; ++nt) {
                const short8 bf = *(const short8*)&Vt[nt * 16 + lm][k0 + qd * 8];
                #pragma unroll
                for (int mt = 0; mt < 2; ++mt)
                    pacc[mt][nt] = __builtin_amdgcn_mfma_f32_16x16x32_bf16(paf[mt], bf, pacc[mt][nt], 0, 0, 0);
            }
        }
    }

    // single atomic pass: remap flat(h,t,d) -> row = b*32 + h*16 + (t>>1),
    // col = (t&1)*256 + d
    #pragma unroll
    for (int mt = 0; mt < 2; ++mt)
        #pragma unroll
        for (int nt = 0; nt < 16; ++nt) {
            const int d = nt * 16 + lm;
            #pragma unroll
            for (int reg = 0; reg < 4; ++reg) {
                const int t = mt * 16 + qd * 4 + reg;
                const int row = b * 32 + h * 16 + (t >> 1);
                const int col = (t & 1) * 256 + d;
                atomicAdd(&acc[(size_t)row * 512 + col], pacc[mt][nt][reg]);
            }
        }
}

// ---------------------------------------------------------------------------
// r7 fused attention (fallback when ws < 21 MB)
// ---------------------------------------------------------------------------
__global__ __launch_bounds__(256)
void attn(const float* __restrict__ video,
          const float* __restrict__ Wk, const float* __restrict__ bk,
          const float* __restrict__ Wv, const float* __restrict__ bv,
          const unsigned short* __restrict__ q,
          float* __restrict__ acc, int b0) {
    const int a = blockIdx.x, h = blockIdx.y;
    const int tid = threadIdx.x;
    const int w = tid >> 6, lane = tid & 63;
    const int lm = lane & 15, qd = lane >> 4;

    __shared__ __align__(16) unsigned char Ubuf[64 * 520 * 2];
    unsigned short (*Vid)[520] = (unsigned short (*)[520])Ubuf;
    unsigned short (*Vt)[72]   = (unsigned short (*)[72])Ubuf;
    __shared__ __align__(16) unsigned short Kb[64][264];
    __shared__ __align__(16) unsigned short Wc[256][40];
    __shared__ __align__(16) unsigned short Qb[32][264];
    __shared__ __align__(16) unsigned short Pb[32][72];
    __shared__ float Ls[32][68];

    #pragma unroll 4
    for (int it = 0; it < 32; ++it) {
        const int s = tid + it * 256;
        const int r = s >> 7, c4 = (s & 127) * 4;
        float4v f = *(const float4v*)&video[((size_t)(a * 64 + r)) * 512 + c4];
        *(ushort4v*)&Vid[r][c4] = (ushort4v){f2bf(f.x), f2bf(f.y), f2bf(f.z), f2bf(f.w)};
    }
    __syncthreads();
    {
        float4v kacc[16];
        #pragma unroll
        for (int nt = 0; nt < 16; ++nt) kacc[nt] = (float4v){0.f, 0.f, 0.f, 0.f};
        for (int k0 = 0; k0 < 512; k0 += 32) {
            #pragma unroll
            for (int it = 0; it < 8; ++it) {
                const int s = tid + it * 256;
                const int r = s >> 3, c4 = (s & 7) * 4;
                float4v f = *(const float4v*)&Wk[((size_t)(h * 256 + r)) * 512 + k0 + c4];
                *(ushort4v*)&Wc[r][c4] = (ushort4v){f2bf(f.x), f2bf(f.y), f2bf(f.z), f2bf(f.w)};
            }
            __syncthreads();
            const short8 af = *(const short8*)&Vid[w * 16 + lm][k0 + qd * 8];
            #pragma unroll
            for (int nt = 0; nt < 16; ++nt) {
                const short8 bf = *(const short8*)&Wc[nt * 16 + lm][qd * 8];
                kacc[nt] = __builtin_amdgcn_mfma_f32_16x16x32_bf16(af, bf, kacc[nt], 0, 0, 0);
            }
            __syncthreads();
        }
        #pragma unroll
        for (int nt = 0; nt < 16; ++nt) {
            const int d = nt * 16 + lm;
            const float bb = bk[h * 256 + d];
            #pragma unroll
            for (int reg = 0; reg < 4; ++reg)
                Kb[w * 16 + qd * 4 + reg][d] = f2bf(kacc[nt][reg] + bb);
        }
    }
    {
        float4v vacc[16];
        #pragma unroll
        for (int nt = 0; nt < 16; ++nt) vacc[nt] = (float4v){0.f, 0.f, 0.f, 0.f};
        for (int k0 = 0; k0 < 512; k0 += 32) {
            #pragma unroll
            for (int it = 0; it < 8; ++it) {
                const int s = tid + it * 256;
                const int r = s >> 3, c4 = (s & 7) * 4;
                float4v f = *(const float4v*)&Wv[((size_t)(h * 256 + r)) * 512 + k0 + c4];
                *(ushort4v*)&Wc[r][c4] = (ushort4v){f2bf(f.x), f2bf(f.y), f2bf(f.z), f2bf(f.w)};
            }
            __syncthreads();
            const short8 af = *(const short8*)&Vid[w * 16 + lm][k0 + qd * 8];
            #pragma unroll
            for (int nt = 0; nt < 16; ++nt) {
                const short8 bf = *(const short8*)&Wc[nt * 16 + lm][qd * 8];
                vacc[nt] = __builtin_amdgcn_mfma_f32_16x16x32_bf16(af, bf, vacc[nt], 0, 0, 0);
            }
            __syncthreads();
        }
        #pragma unroll
        for (int nt = 0; nt < 16; ++nt) {
            const int d = nt * 16 + lm;
            const float bb = bv[h * 256 + d];
            *(ushort4v*)&Vt[d][w * 16 + qd * 4] =
                (ushort4v){f2bf(vacc[nt][0] + bb), f2bf(vacc[nt][1] + bb),
                           f2bf(vacc[nt][2] + bb), f2bf(vacc[nt][3] + bb)};
        }
    }

    const int m0  = (w & 1) * 16;
    const int nb  = (w >> 1) * 2;
    const int nb2 = (w >> 1) * 8;

    for (int bl = 0; bl < 32; ++bl) {
        const int b = b0 + bl;
        __syncthreads();
        #pragma unroll
        for (int it = 0; it < 4; ++it) {
            const int s = tid + it * 256;
            const int r = s >> 5, c8 = (s & 31) * 8;
            *(short8*)&Qb[r][c8] =
                *(const short8*)&q[((size_t)(b * 32 + r)) * 512 + h * 256 + c8];
        }
        __syncthreads();
        {
            float4v lacc[2];
            lacc[0] = (float4v){0.f, 0.f, 0.f, 0.f};
            lacc[1] = (float4v){0.f, 0.f, 0.f, 0.f};
            for (int k0 = 0; k0 < 256; k0 += 32) {
                const short8 af = *(const short8*)&Qb[m0 + lm][k0 + qd * 8];
                #pragma unroll
                for (int j = 0; j < 2; ++j) {
                    const short8 bf = *(const short8*)&Kb[(nb + j) * 16 + lm][k0 + qd * 8];
                    lacc[j] = __builtin_amdgcn_mfma_f32_16x16x32_bf16(af, bf, lacc[j], 0, 0, 0);
                }
            }
            #pragma unroll
            for (int j = 0; j < 2; ++j)
                #pragma unroll
                for (int reg = 0; reg < 4; ++reg)
                    Ls[m0 + qd * 4 + reg][(nb + j) * 16 + lm] = lacc[j][reg] * 0.0625f;
        }
        __syncthreads();
        {
            const int t = tid >> 3, s = tid & 7;
            float4v x0 = *(const float4v*)&Ls[t][s * 8];
            float4v x1 = *(const float4v*)&Ls[t][s * 8 + 4];
            float m = fmaxf(fmaxf(fmaxf(x0.x, x0.y), fmaxf(x0.z, x0.w)),
                            fmaxf(fmaxf(x1.x, x1.y), fmaxf(x1.z, x1.w)));
            m = fmaxf(m, __shfl_xor(m, 1));
            m = fmaxf(m, __shfl_xor(m, 2));
            m = fmaxf(m, __shfl_xor(m, 4));
            float e[8];
            e[0] = __expf(x0.x - m); e[1] = __expf(x0.y - m);
            e[2] = __expf(x0.z - m); e[3] = __expf(x0.w - m);
            e[4] = __expf(x1.x - m); e[5] = __expf(x1.y - m);
            e[6] = __expf(x1.z - m); e[7] = __expf(x1.w - m);
            float sm = e[0] + e[1] + e[2] + e[3] + e[4] + e[5] + e[6] + e[7];
            sm += __shfl_xor(sm, 1);
            sm += __shfl_xor(sm, 2);
            sm += __shfl_xor(sm, 4);
            const float inv = 1.f / sm;
            *(ushort4v*)&Pb[t][s * 8] =
                (ushort4v){f2bf(e[0] * inv), f2bf(e[1] * inv), f2bf(e[2] * inv), f2bf(e[3] * inv)};
            *(ushort4v*)&Pb[t][s * 8 + 4] =
                (ushort4v){f2bf(e[4] * inv), f2bf(e[5] * inv), f2bf(e[6] * inv), f2bf(e[7] * inv)};
        }
        __syncthreads();
        {
            float4v pacc[8];
            #pragma unroll
            for (int j = 0; j < 8; ++j) pacc[j] = (float4v){0.f, 0.f, 0.f, 0.f};
            #pragma unroll
            for (int k0 = 0; k0 < 64; k0 += 32) {
                const short8 af = *(const short8*)&Pb[m0 + lm][k0 + qd * 8];
                #pragma unroll
                for (int j = 0; j < 8; ++j) {
                    const short8 bf = *(const short8*)&Vt[(nb2 + j) * 16 + lm][k0 + qd * 8];
                    pacc[j] = __builtin_amdgcn_mfma_f32_16x16x32_bf16(af, bf, pacc[j], 0, 0, 0);
                }
            }
            #pragma unroll
            for (int j = 0; j < 8; ++j) {
                const int d = (nb2 + j) * 16 + lm;
                #pragma unroll
                for (int reg = 0; reg < 4; ++reg) {
                    const int t   = m0 + qd * 4 + reg;
                    const int row = bl * 32 + h * 16 + (t >> 1);
                    const int e   = (t & 1) * 256 + d;
                    atomicAdd(&acc[(size_t)row * 512 + e], pacc[j][reg]);
                }
            }
        }
    }
}

// ---------------------------------------------------------------------------
// Output projection (fp32 VALU; acc must not be bf16-rounded).
// ---------------------------------------------------------------------------
__global__ __launch_bounds__(256)
void gemm_outp(const float* __restrict__ A, const float* __restrict__ W,
               const float* __restrict__ bias, float* __restrict__ C, int rowoff) {
    __shared__ float As[16][68];
    __shared__ float Ws[16][68];
    const int tid = threadIdx.x;
    const int bi = blockIdx.x * 64, bj = blockIdx.y * 64;
    const int tx = tid & 15, ty = tid >> 4;
    const int lrow = tid >> 2, lk = (tid & 3) * 4;
    float acc[4][4] = {};
    for (int k0 = 0; k0 < 512; k0 += 16) {
        #pragma unroll
        for (int u = 0; u < 4; ++u) {
            As[lk + u][lrow] = A[(size_t)(bi + lrow) * 512 + k0 + lk + u];
            Ws[lk + u][lrow] = W[(size_t)(bj + lrow) * 512 + k0 + lk + u];
        }
        __syncthreads();
        #pragma unroll
        for (int kk = 0; kk < 16; ++kk) {
            float a[4], w[4];
            #pragma unroll
            for (int u = 0; u < 4; ++u) { a[u] = As[kk][ty * 4 + u]; w[u] = Ws[kk][tx * 4 + u]; }
            #pragma unroll
            for (int i = 0; i < 4; ++i)
                #pragma unroll
                for (int j = 0; j < 4; ++j)
                    acc[i][j] += a[i] * w[j];
        }
        __syncthreads();
    }
    #pragma unroll
    for (int i = 0; i < 4; ++i) {
        const int g = rowoff + bi + ty * 4 + i;
        #pragma unroll
        for (int j = 0; j < 4; ++j) {
            const int c = bj + tx * 4 + j;
            C[(size_t)g * 512 + c] = acc[i][j] * (1.f / 128.f) + bias[c];
        }
    }
}

extern "C" void kernel_launch(void* const* d_in, const int* in_sizes, int n_in,
                              void* d_out, int out_size, void* d_ws, size_t ws_size,
                              hipStream_t stream) {
    const float* text  = (const float*)d_in[0];
    const float* video = (const float*)d_in[1];
    const float* Wq = (const float*)d_in[2];
    const float* bq = (const float*)d_in[3];
    const float* Wk = (const float*)d_in[4];
    const float* bk = (const float*)d_in[5];
    const float* Wv = (const float*)d_in[6];
    const float* bv = (const float*)d_in[7];
    const float* Wo = (const float*)d_in[8];
    const float* bo = (const float*)d_in[9];
    unsigned short* qbf = (unsigned short*)d_out;  // q bf16 [2048][512] in d_out [0,2MB)
    float* out = (float*)d_out;

    qproj<<<dim3(32, 8), 256, 0, stream>>>(text, Wq, bq, qbf);

    if (ws_size >= (21u << 20)) {
        // Plan A: K/V precomputed to ws, register-accumulated attention.
        // ws: Kg bf16 [2][128][64][256] @0 (8MB); Vtg bf16 [2][128][256][64] @8MB;
        //     acc fp32 [2048][512] @16MB (4MB). Total 20MB.
        unsigned short* Kg  = (unsigned short*)d_ws;
        unsigned short* Vtg = (unsigned short*)((char*)d_ws + (8u << 20));
        float*          acc = (float*)((char*)d_ws + (16u << 20));

        kvproj<<<dim3(NVID, HEADS), 256, 0, stream>>>(video, Wk, bk, Wv, bv, Kg, Vtg);
        hipMemsetAsync(acc, 0, 1u << 22, stream);
        attn_acc<<<dim3(16, 2, 8), 512, 0, stream>>>(Kg, Vtg, qbf, acc);
        gemm_outp<<<dim3(32, 8), 256, 0, stream>>>(acc, Wo, bo, out, 0);
    } else {
        // Fallback (r7 path): fused attention, 2MB ws.
        float* acc = (float*)d_ws;
        for (int half = 1; half >= 0; --half) {
            hipMemsetAsync(acc, 0, 1u << 21, stream);
            attn<<<dim3(NVID, HEADS), 256, 0, stream>>>(video, Wk, bk, Wv, bv, qbf, acc, half * 32);
            gemm_outp<<<dim3(16, 8), 256, 0, stream>>>(acc, Wo, bo, out, half * 1024);
        }
    }
}

// Round 9
// 260.315 us; speedup vs baseline: 17.7065x; 1.1406x over previous
//
#include <hip/hip_runtime.h>
#include <hip/hip_bf16.h>
#include <math.h>

// Problem constants
#define EMBED  512
#define HEADS  2
#define HDIM   256
#define NTEXT  64
#define NWORD  32
#define NVID   128
#define NFRM   64

typedef __attribute__((ext_vector_type(8))) short      short8;    // 8 bf16 = A/B frag
typedef __attribute__((ext_vector_type(8))) unsigned short ushort8;
typedef __attribute__((ext_vector_type(4))) float      float4v;   // C/D frag
typedef __attribute__((ext_vector_type(4))) unsigned short ushort4v;

__device__ __forceinline__ unsigned short f2bf(float x) {
    __hip_bfloat16 h = __float2bfloat16(x);
    return *(unsigned short*)&h;
}

// ===========================================================================
// proj_qkv: unified projection GEMM. Grid (288, 8), 256 thr.
//   mb <  32 : q  = (text @ Wq^T + bq)/16 -> bf16 row-major [2048][512] (d_out)
//   mb < 160 : K  = video[a]@Wk^T + bk    -> frag-major Kgf[h][a][nt4][kq8][l64][j8]
//   else     : V  = video[a]@Wv^T + bv    -> frag-major Vgf[h][a][ntd16][kqv2][l64][j8]
// Frag conventions (match r7/r8-verified MFMA usage):
//   QK B-frag (K): lane l holds K[v = nt*16+(l&15)][d = kq*32+(l>>4)*8+j]
//   PV B-frag (V): lane l holds V[v = kqv*32+(l>>4)*8+j][d = ntd*16+(l&15)]
// ===========================================================================
__global__ __launch_bounds__(256)
void proj_qkv(const float* __restrict__ text, const float* __restrict__ video,
              const float* __restrict__ Wq, const float* __restrict__ bq,
              const float* __restrict__ Wk, const float* __restrict__ bk,
              const float* __restrict__ Wv, const float* __restrict__ bv,
              unsigned short* __restrict__ qout,
              unsigned short* __restrict__ Kgf, unsigned short* __restrict__ Vgf) {
    const int mb = blockIdx.x, nb = blockIdx.y;
    const int bj = nb * 64;
    const float *A, *W, *bias;
    int op, arow, a = 0;
    if (mb < 32)       { op = 0; A = text;  W = Wq; bias = bq; arow = mb * 64; }
    else if (mb < 160) { op = 1; A = video; W = Wk; bias = bk; a = mb - 32;  arow = a * 64; }
    else               { op = 2; A = video; W = Wv; bias = bv; a = mb - 160; arow = a * 64; }

    // LDS: Ab[64][40] + Wb[64][40] (k-loop) unioned with Eb[64][72] (epilogue)
    __shared__ __align__(16) unsigned char smem[64 * 40 * 2 * 2];  // 10240 B
    unsigned short (*Ab)[40] = (unsigned short (*)[40])smem;
    unsigned short (*Wb)[40] = (unsigned short (*)[40])(smem + 5120);
    unsigned short (*Eb)[72] = (unsigned short (*)[72])smem;       // 9216 B <= 10240

    const int tid = threadIdx.x;
    const int w = tid >> 6, lane = tid & 63;
    const int lm = lane & 15, qd = lane >> 4;

    float4v acc[4];
    #pragma unroll
    for (int nt = 0; nt < 4; ++nt) acc[nt] = (float4v){0.f, 0.f, 0.f, 0.f};

    for (int k0 = 0; k0 < 512; k0 += 32) {
        #pragma unroll
        for (int it = 0; it < 2; ++it) {
            const int s = tid + it * 256;          // 0..511 float4 slots
            const int r = s >> 3, c4 = (s & 7) * 4;
            float4v fa = *(const float4v*)&A[(size_t)(arow + r) * 512 + k0 + c4];
            float4v fw = *(const float4v*)&W[(size_t)(bj + r) * 512 + k0 + c4];
            *(ushort4v*)&Ab[r][c4] = (ushort4v){f2bf(fa.x), f2bf(fa.y), f2bf(fa.z), f2bf(fa.w)};
            *(ushort4v*)&Wb[r][c4] = (ushort4v){f2bf(fw.x), f2bf(fw.y), f2bf(fw.z), f2bf(fw.w)};
        }
        __syncthreads();
        const short8 af = *(const short8*)&Ab[w * 16 + lm][qd * 8];
        #pragma unroll
        for (int nt = 0; nt < 4; ++nt) {
            const short8 bf = *(const short8*)&Wb[nt * 16 + lm][qd * 8];
            acc[nt] = __builtin_amdgcn_mfma_f32_16x16x32_bf16(af, bf, acc[nt], 0, 0, 0);
        }
        __syncthreads();
    }

    if (op == 0) {
        // q epilogue: scale by 1/16 (folds the logit scale), bf16 row-major
        #pragma unroll
        for (int nt = 0; nt < 4; ++nt) {
            const int c = bj + nt * 16 + lm;
            const float bb = bias[c];
            #pragma unroll
            for (int reg = 0; reg < 4; ++reg) {
                const int r = arow + w * 16 + qd * 4 + reg;
                qout[(size_t)r * 512 + c] = f2bf((acc[nt][reg] + bb) * 0.0625f);
            }
        }
        return;
    }

    const int h = bj >> 8;
    const int bj_rel = bj & 255;

    if (op == 1) {
        // K: write tile row-major to Eb[v][d_local], then frag-major spill
        #pragma unroll
        for (int nt = 0; nt < 4; ++nt) {
            const int dl = nt * 16 + lm;
            const float bb = bias[bj + dl];
            #pragma unroll
            for (int reg = 0; reg < 4; ++reg)
                Eb[w * 16 + qd * 4 + reg][dl] = f2bf(acc[nt][reg] + bb);
        }
        __syncthreads();
        const size_t base = ((size_t)(h * 128 + a)) * 16384;
        #pragma unroll
        for (int i = 0; i < 2; ++i) {
            const int s = tid + i * 256;           // 0..511 frag slots
            const int ntf = s >> 7, kqr = (s >> 6) & 1, l = s & 63;
            const int v = ntf * 16 + (l & 15);
            const int dl = kqr * 32 + (l >> 4) * 8;
            ushort8 val = *(const ushort8*)&Eb[v][dl];
            *(ushort8*)&Kgf[base + ((size_t)(ntf * 8 + (bj_rel >> 5) + kqr) * 64 + l) * 8] = val;
        }
    } else {
        // V: write tile TRANSPOSED to Eb[d_local][v], then frag-major spill
        #pragma unroll
        for (int nt = 0; nt < 4; ++nt) {
            const int dl = nt * 16 + lm;
            const float bb = bias[bj + dl];
            #pragma unroll
            for (int reg = 0; reg < 4; ++reg)
                Eb[dl][w * 16 + qd * 4 + reg] = f2bf(acc[nt][reg] + bb);
        }
        __syncthreads();
        const size_t base = ((size_t)(h * 128 + a)) * 16384;
        #pragma unroll
        for (int i = 0; i < 2; ++i) {
            const int s = tid + i * 256;
            const int ntr = s >> 7, kqv = (s >> 6) & 1, l = s & 63;
            const int dl = ntr * 16 + (l & 15);
            const int v0 = kqv * 32 + (l >> 4) * 8;
            ushort8 val = *(const ushort8*)&Eb[dl][v0];
            *(ushort8*)&Vgf[base + ((size_t)(((bj_rel >> 4) + ntr) * 2 + kqv) * 64 + l) * 8] = val;
        }
    }
}

// ===========================================================================
// attn_acc: grid (16 vid-chunks, 2 h, 16 text-groups), 256 thr (4 waves),
// 2 blocks/CU (LDS = exactly 80 KB). Wave w owns text b = zb*4 + w.
// Per vid: stage frag-major K/V (contiguous b128), QK with hoisted Q regs,
// in-register softmax (shuffle over lm bits), P -> wave-private frag-major
// LDS patch, PV accumulated in VGPR/AGPR across vids. One atomic pass at end.
// ===========================================================================
__global__ __launch_bounds__(256, 2)
void attn_acc(const unsigned short* __restrict__ Kgf,
              const unsigned short* __restrict__ Vgf,
              const unsigned short* __restrict__ q,   // bf16 [2048][512], pre-scaled 1/16
              float* __restrict__ acc) {
    const int chunk = blockIdx.x;
    const int h = blockIdx.y;
    const int zb = blockIdx.z;
    const int tid = threadIdx.x;
    const int w = tid >> 6, lane = tid & 63;
    const int lm = lane & 15, qd = lane >> 4;
    const int b = zb * 4 + w;

    __shared__ __align__(16) unsigned short KfL[16384];   // 32 KB
    __shared__ __align__(16) unsigned short VfL[16384];   // 32 KB
    __shared__ __align__(16) unsigned short PfL[8192];    // 16 KB (4 KB per wave)
    const int wbase = w * 2048;

    // hoist Q A-frags (wave-invariant across vids): 16 x short8 = 64 VGPRs
    short8 qf[2][8];
    #pragma unroll
    for (int mt = 0; mt < 2; ++mt)
        #pragma unroll
        for (int kq = 0; kq < 8; ++kq)
            qf[mt][kq] = *(const short8*)
                &q[((size_t)(b * 32 + mt * 16 + lm)) * 512 + h * 256 + kq * 32 + qd * 8];

    float4v pacc[2][16];
    #pragma unroll
    for (int mt = 0; mt < 2; ++mt)
        #pragma unroll
        for (int nt = 0; nt < 16; ++nt) pacc[mt][nt] = (float4v){0.f, 0.f, 0.f, 0.f};

    for (int ai = 0; ai < 8; ++ai) {
        const int a = chunk * 8 + ai;
        __syncthreads();   // all waves done reading previous K/V
        const size_t kb = ((size_t)(h * 128 + a)) * 16384;
        #pragma unroll
        for (int i = 0; i < 8; ++i) {
            const int s = tid + i * 256;           // 0..2047 ushort8 slots
            *(ushort8*)&KfL[s * 8] = *(const ushort8*)&Kgf[kb + (size_t)s * 8];
            *(ushort8*)&VfL[s * 8] = *(const ushort8*)&Vgf[kb + (size_t)s * 8];
        }
        __syncthreads();

        // QK: logits (already scaled via q/16)
        float4v lacc[2][4];
        #pragma unroll
        for (int mt = 0; mt < 2; ++mt)
            #pragma unroll
            for (int nt = 0; nt < 4; ++nt) lacc[mt][nt] = (float4v){0.f, 0.f, 0.f, 0.f};
        #pragma unroll
        for (int kq = 0; kq < 8; ++kq) {
            #pragma unroll
            for (int nt = 0; nt < 4; ++nt) {
                const short8 kf = *(const short8*)&KfL[((nt * 8 + kq) * 64 + lane) * 8];
                lacc[0][nt] = __builtin_amdgcn_mfma_f32_16x16x32_bf16(qf[0][kq], kf, lacc[0][nt], 0, 0, 0);
                lacc[1][nt] = __builtin_amdgcn_mfma_f32_16x16x32_bf16(qf[1][kq], kf, lacc[1][nt], 0, 0, 0);
            }
        }

        // softmax over v (64 = 4 nt in-lane x 16 lm cross-lane), per (mt,reg) row
        #pragma unroll
        for (int mt = 0; mt < 2; ++mt) {
            #pragma unroll
            for (int reg = 0; reg < 4; ++reg) {
                const float l0 = lacc[mt][0][reg], l1 = lacc[mt][1][reg];
                const float l2 = lacc[mt][2][reg], l3 = lacc[mt][3][reg];
                float m = fmaxf(fmaxf(l0, l1), fmaxf(l2, l3));
                m = fmaxf(m, __shfl_xor(m, 1));
                m = fmaxf(m, __shfl_xor(m, 2));
                m = fmaxf(m, __shfl_xor(m, 4));
                m = fmaxf(m, __shfl_xor(m, 8));
                const float e0 = __expf(l0 - m), e1 = __expf(l1 - m);
                const float e2 = __expf(l2 - m), e3 = __expf(l3 - m);
                float s = e0 + e1 + e2 + e3;
                s += __shfl_xor(s, 1);
                s += __shfl_xor(s, 2);
                s += __shfl_xor(s, 4);
                s += __shfl_xor(s, 8);
                const float inv = 1.f / s;
                // P -> wave-private frag-major patch (A-frag for PV)
                const int lt = qd * 4 + reg;
                const int jj = lm & 7;
                const int lsub = lt + 16 * ((lm >> 3));       // nt even part
                PfL[wbase + ((mt * 2 + 0) * 64 + lsub) * 8 + jj]            = f2bf(e0 * inv);  // nt=0
                PfL[wbase + ((mt * 2 + 0) * 64 + lsub + 32) * 8 + jj]       = f2bf(e1 * inv);  // nt=1
                PfL[wbase + ((mt * 2 + 1) * 64 + lsub) * 8 + jj]            = f2bf(e2 * inv);  // nt=2
                PfL[wbase + ((mt * 2 + 1) * 64 + lsub + 32) * 8 + jj]       = f2bf(e3 * inv);  // nt=3
            }
        }

        // PV: accumulate across vids in registers (wave-private Pf: no barrier)
        #pragma unroll
        for (int kqv = 0; kqv < 2; ++kqv) {
            const short8 p0 = *(const short8*)&PfL[wbase + ((0 * 2 + kqv) * 64 + lane) * 8];
            const short8 p1 = *(const short8*)&PfL[wbase + ((1 * 2 + kqv) * 64 + lane) * 8];
            #pragma unroll
            for (int nt = 0; nt < 16; ++nt) {
                const short8 vf = *(const short8*)&VfL[((nt * 2 + kqv) * 64 + lane) * 8];
                pacc[0][nt] = __builtin_amdgcn_mfma_f32_16x16x32_bf16(p0, vf, pacc[0][nt], 0, 0, 0);
                pacc[1][nt] = __builtin_amdgcn_mfma_f32_16x16x32_bf16(p1, vf, pacc[1][nt], 0, 0, 0);
            }
        }
    }

    // single atomic pass: remap flat(h,t,d) -> row = b*32 + h*16 + (t>>1),
    // col = (t&1)*256 + d   (verified r6-r8)
    #pragma unroll
    for (int mt = 0; mt < 2; ++mt)
        #pragma unroll
        for (int nt = 0; nt < 16; ++nt) {
            const int d = nt * 16 + lm;
            #pragma unroll
            for (int reg = 0; reg < 4; ++reg) {
                const int t = mt * 16 + qd * 4 + reg;
                const int row = b * 32 + h * 16 + (t >> 1);
                const int col = (t & 1) * 256 + d;
                atomicAdd(&acc[(size_t)row * 512 + col], pacc[mt][nt][reg]);
            }
        }
}

// ===========================================================================
// proj_o: out = (acc/128) @ Wo^T + bo, fp32 out. MFMA, 32x64 tiles,
// grid (64, 8) = 512 blocks (2/CU). acc pre-scaled by 1/128 at staging.
// ===========================================================================
__global__ __launch_bounds__(256)
void proj_o(const float* __restrict__ A, const float* __restrict__ W,
            const float* __restrict__ bias, float* __restrict__ C) {
    __shared__ __align__(16) unsigned short Ab[32][40];
    __shared__ __align__(16) unsigned short Wb[64][40];
    const int tid = threadIdx.x;
    const int bi = blockIdx.x * 32, bj = blockIdx.y * 64;
    const int w = tid >> 6, lane = tid & 63;
    const int lm = lane & 15, qd = lane >> 4;
    const int mt = w & 1, np = (w >> 1) * 2;

    float4v acc2[2];
    acc2[0] = (float4v){0.f, 0.f, 0.f, 0.f};
    acc2[1] = (float4v){0.f, 0.f, 0.f, 0.f};

    for (int k0 = 0; k0 < 512; k0 += 32) {
        {
            const int s = tid;                      // A: 32x32 fp32 = 256 slots
            const int r = s >> 3, c4 = (s & 7) * 4;
            float4v fa = *(const float4v*)&A[(size_t)(bi + r) * 512 + k0 + c4];
            fa *= 0.0078125f;   // 1/128 mean
            *(ushort4v*)&Ab[r][c4] = (ushort4v){f2bf(fa.x), f2bf(fa.y), f2bf(fa.z), f2bf(fa.w)};
        }
        #pragma unroll
        for (int it = 0; it < 2; ++it) {            // W: 64x32 fp32 = 512 slots
            const int s = tid + it * 256;
            const int r = s >> 3, c4 = (s & 7) * 4;
            float4v fw = *(const float4v*)&W[(size_t)(bj + r) * 512 + k0 + c4];
            *(ushort4v*)&Wb[r][c4] = (ushort4v){f2bf(fw.x), f2bf(fw.y), f2bf(fw.z), f2bf(fw.w)};
        }
        __syncthreads();
        const short8 af = *(const short8*)&Ab[mt * 16 + lm][qd * 8];
        #pragma unroll
        for (int j = 0; j < 2; ++j) {
            const short8 bf = *(const short8*)&Wb[(np + j) * 16 + lm][qd * 8];
            acc2[j] = __builtin_amdgcn_mfma_f32_16x16x32_bf16(af, bf, acc2[j], 0, 0, 0);
        }
        __syncthreads();
    }
    #pragma unroll
    for (int j = 0; j < 2; ++j) {
        const int c = bj + (np + j) * 16 + lm;
        const float bb = bias[c];
        #pragma unroll
        for (int reg = 0; reg < 4; ++reg) {
            const int r = bi + mt * 16 + qd * 4 + reg;
            C[(size_t)r * 512 + c] = acc2[j][reg] + bb;
        }
    }
}

extern "C" void kernel_launch(void* const* d_in, const int* in_sizes, int n_in,
                              void* d_out, int out_size, void* d_ws, size_t ws_size,
                              hipStream_t stream) {
    const float* text  = (const float*)d_in[0];
    const float* video = (const float*)d_in[1];
    const float* Wq = (const float*)d_in[2];
    const float* bq = (const float*)d_in[3];
    const float* Wk = (const float*)d_in[4];
    const float* bk = (const float*)d_in[5];
    const float* Wv = (const float*)d_in[6];
    const float* bv = (const float*)d_in[7];
    const float* Wo = (const float*)d_in[8];
    const float* bo = (const float*)d_in[9];

    // ws (20 MB, proven >= 21 MB available in r8):
    //   Kgf bf16 frag-major [2][128][4][8][64][8] @ 0     (8 MB)
    //   Vgf bf16 frag-major [2][128][16][2][64][8] @ 8 MB (8 MB)
    //   acc fp32 [2048][512] @ 16 MB                      (4 MB)
    // q bf16 [2048][512] (pre-scaled 1/16) lives in d_out [0,2MB), consumed by
    // attn_acc before proj_o overwrites d_out.
    unsigned short* Kgf = (unsigned short*)d_ws;
    unsigned short* Vgf = (unsigned short*)((char*)d_ws + (8u << 20));
    float*          acc = (float*)((char*)d_ws + (16u << 20));
    unsigned short* qbf = (unsigned short*)d_out;
    float*          out = (float*)d_out;

    hipMemsetAsync(acc, 0, 1u << 22, stream);
    proj_qkv<<<dim3(288, 8), 256, 0, stream>>>(text, video, Wq, bq, Wk, bk, Wv, bv,
                                               qbf, Kgf, Vgf);
    attn_acc<<<dim3(16, 2, 16), 256, 0, stream>>>(Kgf, Vgf, qbf, acc);
    proj_o<<<dim3(64, 8), 256, 0, stream>>>(acc, Wo, bo, out);
}